// Round 4
// baseline (234.288 us; speedup 1.0000x reference)
//
#include <hip/hip_runtime.h>

// CapsNet dynamic routing, MI355X. Never materialize u_hat.
//  s-pass:  s[b][jd] = sum_ki x[b][ki] * (c[i][j]*W2[jd][ki])  — MFMA, split-K 256 chunks, dbuf-pipelined LDS
//  agree:   Z_T[jd][ki] = sum_b v[jd][b]*x[b][ki] (LDS-free MFMA from xbfT/vbT); epilogue dots with W2 -> bT
// R4: fix pack_xt write loop (u<2 -> u<4; upper 32 ki-rows of each tile were left as poison in R3).

typedef __attribute__((ext_vector_type(8))) __bf16 bf16x8;
typedef __attribute__((ext_vector_type(4))) float  f32x4;
typedef __attribute__((ext_vector_type(8))) unsigned short u16x8;
typedef __attribute__((ext_vector_type(4))) unsigned int  u32x4;

#define DI __device__ __forceinline__

DI float bf2f(unsigned short u){ unsigned int x = ((unsigned int)u) << 16; return __builtin_bit_cast(float, x); }
DI unsigned short f2bf(float f){
  unsigned int u = __builtin_bit_cast(unsigned int, f);
  u += 0x7fffu + ((u >> 16) & 1u);
  return (unsigned short)(u >> 16);
}
DI unsigned int cvtpk(float lo, float hi){            // packed RNE f32->bf16 pair
  unsigned int r;
  asm("v_cvt_pk_bf16_f32 %0, %1, %2" : "=v"(r) : "v"(lo), "v"(hi));
  return r;
}

constexpr int Ci = 4096, Kk = 32, Jj = 10, Dd = 16, Bb = 128;
constexpr int KI = Ci * Kk;    // 131072, ki = k*4096 + i
constexpr int JDt = Jj * Dd;   // 160, jd = j*16 + d
constexpr int NCH = 256, CK = 512;

// workspace layout (bytes), ~96.8 MB
constexpr size_t OFF_W2 = 0;
constexpr size_t SZ_W2  = (size_t)JDt * KI * 2;       // 41,943,040  w2[m][i] == [jd][ki]
constexpr size_t OFF_XT = OFF_W2 + SZ_W2;
constexpr size_t SZ_XT  = (size_t)KI * Bb * 2;        // 33,554,432  xbfT[ki][b]
constexpr size_t OFF_BT = OFF_XT + SZ_XT;
constexpr size_t SZ_BT  = (size_t)Jj * Ci * 4;        // 163,840
constexpr size_t OFF_CT = OFF_BT + SZ_BT;
constexpr size_t OFF_VBT = OFF_CT + SZ_BT;
constexpr size_t SZ_VBT = (size_t)JDt * Bb * 2;
constexpr size_t OFF_SP = OFF_VBT + SZ_VBT;
constexpr size_t SZ_SP  = (size_t)NCH * Bb * JDt * 4; // 20,971,520

// ---- pack W: f32 W[i][m] (row 5120, m=jd*32+k) -> bf16 w2[m][i]; 64m x 128i tiles ----
__global__ __launch_bounds__(256) void pack_w(const float* __restrict__ W, unsigned short* __restrict__ w2){
  __shared__ float tile[128][65];                     // [i][m], pad 65
  const int mt = blockIdx.x % 80, it = blockIdx.x / 80;
  const int m0 = mt * 64, i0 = it * 128;
  #pragma unroll
  for(int u=0; u<8; u++){                             // read: 16 i-rows x 64 m per iter, 256B/row
    int e = threadIdx.x + 256*u;
    int il = e >> 4, q = e & 15;
    float4 v = *(const float4*)(W + (size_t)(i0+il)*5120 + m0 + q*4);
    tile[il][q*4+0]=v.x; tile[il][q*4+1]=v.y; tile[il][q*4+2]=v.z; tile[il][q*4+3]=v.w;
  }
  __syncthreads();
  #pragma unroll
  for(int u=0; u<4; u++){                             // write: 16 m-rows x 128 i per iter, 256B/row
    int e = threadIdx.x + 256*u;
    int ml = e >> 4, q = e & 15;                      // q = 8-i group
    u32x4 o;
    o[0]=cvtpk(tile[q*8+0][ml], tile[q*8+1][ml]);
    o[1]=cvtpk(tile[q*8+2][ml], tile[q*8+3][ml]);
    o[2]=cvtpk(tile[q*8+4][ml], tile[q*8+5][ml]);
    o[3]=cvtpk(tile[q*8+6][ml], tile[q*8+7][ml]);
    *(u32x4*)(w2 + (size_t)(m0+ml)*Ci + i0 + q*8) = o;
  }
}

// ---- pack xT: f32 x[b][ki] -> bf16 xbfT[ki][b]; 128b x 64ki tiles; tail blocks zero bT ----
__global__ __launch_bounds__(256) void pack_xt(const float* __restrict__ x, unsigned short* __restrict__ xT,
                                               float* __restrict__ bT){
  __shared__ float tile[128][65];                     // [b][ki], pad 65
  const int bid = blockIdx.x;
  if(bid >= 2048){                                    // zero bT: 40 blocks x 256 x 16B
    ((f32x4*)bT)[(bid-2048)*256 + threadIdx.x] = f32x4{0.f,0.f,0.f,0.f};
    return;
  }
  const int ki0 = bid * 64;
  #pragma unroll
  for(int u=0; u<8; u++){                             // read: 16 b-rows x 64 ki per iter
    int e = threadIdx.x + 256*u;
    int bl = e >> 4, q = e & 15;
    float4 v = *(const float4*)(x + (size_t)bl*KI + ki0 + q*4);
    tile[bl][q*4+0]=v.x; tile[bl][q*4+1]=v.y; tile[bl][q*4+2]=v.z; tile[bl][q*4+3]=v.w;
  }
  __syncthreads();
  #pragma unroll
  for(int u=0; u<4; u++){                             // write: 16 ki-rows x 128 b per iter (64x16 = 1024 writes)
    int e = threadIdx.x + 256*u;
    int kil = e >> 4, g = e & 15;                     // kil in [0,64), g = 8-b group
    u32x4 o;
    o[0]=cvtpk(tile[g*8+0][kil], tile[g*8+1][kil]);
    o[1]=cvtpk(tile[g*8+2][kil], tile[g*8+3][kil]);
    o[2]=cvtpk(tile[g*8+4][kil], tile[g*8+5][kil]);
    o[3]=cvtpk(tile[g*8+6][kil], tile[g*8+7][kil]);
    *(u32x4*)(xT + (size_t)(ki0+kil)*Bb + g*8) = o;
  }
}

// ---- softmax over i per class j ----
__global__ __launch_bounds__(256) void softmax_k(const float* __restrict__ bT, float* __restrict__ cT){
  const int j = blockIdx.x, tid = threadIdx.x, lane = tid & 63, wid = tid >> 6;
  __shared__ float red[4];
  float vals[16];
  float mx = -3.4e38f;
  #pragma unroll
  for(int u=0; u<16; u++){ vals[u] = bT[j*Ci + tid + 256*u]; mx = fmaxf(mx, vals[u]); }
  #pragma unroll
  for(int o=32; o>0; o>>=1) mx = fmaxf(mx, __shfl_xor(mx, o));
  if(lane == 0) red[wid] = mx;
  __syncthreads();
  mx = fmaxf(fmaxf(red[0],red[1]), fmaxf(red[2],red[3]));
  float sm = 0.f;
  #pragma unroll
  for(int u=0; u<16; u++){ vals[u] = expf(vals[u]-mx); sm += vals[u]; }
  #pragma unroll
  for(int o=32; o>0; o>>=1) sm += __shfl_xor(sm, o);
  __syncthreads();
  if(lane == 0) red[wid] = sm;
  __syncthreads();
  sm = red[0]+red[1]+red[2]+red[3];
  float inv = 1.0f / sm;
  #pragma unroll
  for(int u=0; u<16; u++) cT[j*Ci + tid + 256*u] = vals[u]*inv;
}

// ---- s-pass: dbuf pipeline; stages x from f32 (cvt in-flight), w2 bf16 scaled by c ----
__global__ __launch_bounds__(512) void s_pass(const float* __restrict__ x,
                                              const unsigned short* __restrict__ w2,
                                              const float* __restrict__ cT,
                                              float* __restrict__ spart){
  __shared__ unsigned short xs[2][128*64];    // 2 x 16KB, [b][k] rows 128B, XOR-swizzled
  __shared__ unsigned short wsm[2][160*64];   // 2 x 20KB, [jd][k] rows 128B, swizzled, c-scaled
  const int tid = threadIdx.x, lane = tid & 63, wid = tid >> 6;
  const int wb = wid & 3, wj = wid >> 2;
  const int ki0 = blockIdx.x * CK;
  const float cu = 1.0f/4096.0f;

  const int xb_ = tid >> 3, xsg = tid & 7;    // x rows xb_ and xb_+64, 8-ki group xsg
  f32x4 acc[2][5];
  #pragma unroll
  for(int m=0;m<2;m++)
    #pragma unroll
    for(int n=0;n<5;n++) acc[m][n] = f32x4{0.f,0.f,0.f,0.f};

  float4 xv[4]; u16x8 wv[3]; float4 cv[3][2];

  #define S_LOAD(STEP) { \
    const int kb = ki0 + (STEP)*64; \
    const float* xr = x + (size_t)xb_*KI + kb + xsg*8; \
    xv[0]=*(const float4*)xr; xv[1]=*(const float4*)(xr+4); \
    const float* xr2 = xr + (size_t)64*KI; \
    xv[2]=*(const float4*)xr2; xv[3]=*(const float4*)(xr2+4); \
    const int ib = kb & (Ci-1); \
    _Pragma("unroll") \
    for(int u=0; u<3; u++){ int e = tid + 512*u; if(e < 1280){ \
      int jd = e>>3, sg = e&7; \
      wv[u] = *(const u16x8*)(w2 + (size_t)jd*KI + kb + sg*8); \
      if(cT){ const float* cp = cT + (jd>>4)*Ci + ib + sg*8; \
        cv[u][0] = *(const float4*)cp; cv[u][1] = *(const float4*)(cp+4); } \
    }} }

  #define S_WRITE(BUF) { \
    u32x4 xo; \
    xo[0]=cvtpk(xv[0].x,xv[0].y); xo[1]=cvtpk(xv[0].z,xv[0].w); \
    xo[2]=cvtpk(xv[1].x,xv[1].y); xo[3]=cvtpk(xv[1].z,xv[1].w); \
    *(u32x4*)((char*)xs[BUF] + xb_*128 + ((xsg*16) ^ ((xb_&7)<<4))) = xo; \
    xo[0]=cvtpk(xv[2].x,xv[2].y); xo[1]=cvtpk(xv[2].z,xv[2].w); \
    xo[2]=cvtpk(xv[3].x,xv[3].y); xo[3]=cvtpk(xv[3].z,xv[3].w); \
    *(u32x4*)((char*)xs[BUF] + (xb_+64)*128 + ((xsg*16) ^ ((xb_&7)<<4))) = xo; \
    _Pragma("unroll") \
    for(int u=0; u<3; u++){ int e = tid + 512*u; if(e < 1280){ \
      int jd = e>>3, sg = e&7; \
      float f[8]; \
      _Pragma("unroll") \
      for(int q=0;q<8;q++) f[q] = bf2f(wv[u][q]); \
      if(cT){ \
        f[0]*=cv[u][0].x; f[1]*=cv[u][0].y; f[2]*=cv[u][0].z; f[3]*=cv[u][0].w; \
        f[4]*=cv[u][1].x; f[5]*=cv[u][1].y; f[6]*=cv[u][1].z; f[7]*=cv[u][1].w; \
      } else { \
        _Pragma("unroll") \
        for(int q=0;q<8;q++) f[q] *= cu; \
      } \
      u32x4 wo; \
      wo[0]=cvtpk(f[0],f[1]); wo[1]=cvtpk(f[2],f[3]); \
      wo[2]=cvtpk(f[4],f[5]); wo[3]=cvtpk(f[6],f[7]); \
      *(u32x4*)((char*)wsm[BUF] + jd*128 + ((sg*16) ^ ((jd&7)<<4))) = wo; \
    }} }

  S_LOAD(0); S_WRITE(0);
  __syncthreads();
  int cur = 0;
  for(int step=0; step<8; ++step){
    if(step < 7) S_LOAD(step+1);
    #pragma unroll
    for(int ks=0; ks<2; ks++){
      const int kk2 = (ks*32 + ((lane>>4)<<3)) * 2;
      bf16x8 a[2];
      #pragma unroll
      for(int m=0;m<2;m++){
        int row = wb*32 + m*16 + (lane&15);
        a[m] = *(const bf16x8*)((const char*)xs[cur] + row*128 + (kk2 ^ ((row&7)<<4)));
      }
      #pragma unroll
      for(int n=0;n<5;n++){
        int row = wj*80 + n*16 + (lane&15);
        bf16x8 bb = *(const bf16x8*)((const char*)wsm[cur] + row*128 + (kk2 ^ ((row&7)<<4)));
        acc[0][n] = __builtin_amdgcn_mfma_f32_16x16x32_bf16(a[0], bb, acc[0][n], 0,0,0);
        acc[1][n] = __builtin_amdgcn_mfma_f32_16x16x32_bf16(a[1], bb, acc[1][n], 0,0,0);
      }
    }
    if(step < 7) S_WRITE(cur^1);
    __syncthreads();
    cur ^= 1;
  }
  float* sp = spart + (size_t)blockIdx.x * (Bb*JDt);
  #pragma unroll
  for(int m=0;m<2;m++)
    #pragma unroll
    for(int n=0;n<5;n++)
      #pragma unroll
      for(int r=0;r<4;r++){
        int b  = wb*32 + m*16 + ((lane>>4)<<2) + r;
        int jd = wj*80 + n*16 + (lane&15);
        sp[b*JDt + jd] = acc[m][n][r];
      }
}

// ---- reduce split-K partials + squash ----
__global__ __launch_bounds__(256) void redsq(const float* __restrict__ spart,
                                             float* __restrict__ vout,
                                             unsigned short* __restrict__ vbT){
  const int b = blockIdx.x, tid = threadIdx.x;
  __shared__ float sred[6][JDt];
  __shared__ float sq[JDt];
  __shared__ float scale[Dd];
  if(tid < 240){
    const int g = tid % 40, cg = tid / 40;            // g: jd-quad, cg: chunk group
    f32x4 a = {0.f,0.f,0.f,0.f};
    for(int ch=cg; ch<NCH; ch+=6)
      a += *(const f32x4*)(spart + (size_t)ch*(Bb*JDt) + b*JDt + g*4);
    *(f32x4*)&sred[cg][g*4] = a;
  }
  __syncthreads();
  float s = 0.f;
  if(tid < JDt){
    #pragma unroll
    for(int c=0;c<6;c++) s += sred[c][tid];
    sq[tid] = s*s;
  }
  __syncthreads();
  if(tid < Dd){
    float m = 0.f;
    #pragma unroll
    for(int j=0;j<Jj;j++) m += sq[j*Dd + tid];
    scale[tid] = sqrtf(m) / (1.0f + m);
  }
  __syncthreads();
  if(tid < JDt){
    float v = s * scale[tid & (Dd-1)];
    vout[b*JDt + tid] = v;
    vbT[tid*Bb + b] = f2bf(v);
  }
}

// ---- agree pass: LDS-free. frags direct from vbT[jd][b] and xbfT[ki][b]; epilogue dots W2, atomics to bT ----
__global__ __launch_bounds__(256) void agree_pass(const unsigned short* __restrict__ xT,
                                                  const unsigned short* __restrict__ vbT,
                                                  const unsigned short* __restrict__ w2,
                                                  float* __restrict__ bT){
  const int tid = threadIdx.x, lane = tid & 63, wid = tid >> 6;
  const int wj = wid & 1, wk = wid >> 1;
  const int ki0 = blockIdx.x * 64;
  const int bsl = (lane>>4)<<3;                       // 8-b slice within 32-group
  f32x4 acc[5][2];
  #pragma unroll
  for(int m=0;m<5;m++){ acc[m][0]=f32x4{0,0,0,0}; acc[m][1]=f32x4{0,0,0,0}; }
  #pragma unroll
  for(int ks=0; ks<4; ks++){
    bf16x8 af[5];
    #pragma unroll
    for(int m=0;m<5;m++){
      int jd = wj*80 + m*16 + (lane&15);
      af[m] = *(const bf16x8*)(vbT + jd*Bb + ks*32 + bsl);
    }
    #pragma unroll
    for(int n=0;n<2;n++){
      int kir = ki0 + wk*32 + n*16 + (lane&15);
      bf16x8 bf_ = *(const bf16x8*)(xT + (size_t)kir*Bb + ks*32 + bsl);
      #pragma unroll
      for(int m=0;m<5;m++)
        acc[m][n] = __builtin_amdgcn_mfma_f32_16x16x32_bf16(af[m], bf_, acc[m][n], 0,0,0);
    }
  }
  const int ibase = ki0 & (Ci-1);
  #pragma unroll
  for(int m=0;m<5;m++){
    int j = wj*5 + m;
    #pragma unroll
    for(int n=0;n<2;n++){
      int colg = ki0 + wk*32 + n*16 + (lane&15);
      float s = 0.f;
      #pragma unroll
      for(int r=0;r<4;r++){
        int jdrow = wj*80 + m*16 + ((lane>>4)<<2) + r;
        s += acc[m][n][r] * bf2f(w2[(size_t)jdrow*KI + colg]);
      }
      s += __shfl_xor(s, 16);
      s += __shfl_xor(s, 32);
      if(lane < 16){
        int ig = ibase + wk*32 + n*16 + lane;
        atomicAdd(bT + j*Ci + ig, s * (1.0f/128.0f));
      }
    }
  }
}

extern "C" void kernel_launch(void* const* d_in, const int* in_sizes, int n_in,
                              void* d_out, int out_size, void* d_ws, size_t ws_size,
                              hipStream_t stream) {
  const float* x = (const float*)d_in[0];
  const float* W = (const float*)d_in[1];
  float* out = (float*)d_out;
  char* ws = (char*)d_ws;
  unsigned short* w2  = (unsigned short*)(ws + OFF_W2);
  unsigned short* xT  = (unsigned short*)(ws + OFF_XT);
  float* bT           = (float*)(ws + OFF_BT);
  float* cT           = (float*)(ws + OFF_CT);
  unsigned short* vbT = (unsigned short*)(ws + OFF_VBT);
  float* spart        = (float*)(ws + OFF_SP);

  pack_w<<<2560, 256, 0, stream>>>(W, w2);
  pack_xt<<<2088, 256, 0, stream>>>(x, xT, bT);       // tail 40 blocks zero bT
  for(int t=0; t<3; t++){
    if(t > 0) softmax_k<<<Jj, 256, 0, stream>>>(bT, cT);
    s_pass<<<NCH, 512, 0, stream>>>(x, w2, (t==0)? nullptr : cT, spart);
    redsq<<<Bb, 256, 0, stream>>>(spart, out, vbT);
    if(t < 2) agree_pass<<<KI/64, 256, 0, stream>>>(xT, vbT, w2, bT);
  }
}